// Round 5
// baseline (713.169 us; speedup 1.0000x reference)
//
#include <hip/hip_runtime.h>

#define NNODES 20000
#define FIN 64
#define HDIM 512
#define NEDGE 160000

typedef _Float16 f16;
typedef _Float16 f16x8 __attribute__((ext_vector_type(8)));
typedef float f32x4 __attribute__((ext_vector_type(4)));

#define SLICE ((size_t)NNODES * HDIM)
#define HH ((size_t)HDIM * HDIM)

// ---------------------------------------------------------------- helpers
__device__ __forceinline__ void async_lds16(const void* g, void* lds_base) {
  __builtin_amdgcn_global_load_lds(
      (const __attribute__((address_space(1))) void*)g,
      (__attribute__((address_space(3))) void*)lds_base, 16, 0, 0);
}

// ---------------------------------------------------------------- fused prep
// blocks [0,313): zero deg; [313,25313): cvt x; [25313,25953): W_in transpose
__global__ void k_prep(const float* __restrict__ x, f16* __restrict__ xb,
                       const float* __restrict__ Win, f16* __restrict__ Wint,
                       int* __restrict__ deg) {
  int b = blockIdx.x;
  if (b < 313) {
    int i = b * 256 + threadIdx.x;
    if (i < 4 * NNODES) deg[i] = 0;
  } else if (b < 25313) {
    int i = (b - 313) * 256 + threadIdx.x;
    xb[i] = (f16)x[i];
  } else {
    int i = (b - 25313) * 256 + threadIdx.x;
    int t = i >> 15;
    int rem = i & 32767;
    int nn = rem >> 6;
    int kk = rem & 63;
    Wint[i] = (f16)Win[(size_t)t * 32768 + (size_t)kk * 512 + nn];
  }
}

// W1/W2 [2][6][512][512] f32 -> transposed f16, 6 used slots; LDS 32x32 tiles.
// grid (256, 6): blockIdx.x = tile (bx=kk-tile 0..15, by=nn-tile 0..15)
__global__ __launch_bounds__(256) void k_cvt_w(const float* __restrict__ W1,
                                               const float* __restrict__ W2,
                                               f16* __restrict__ W1t,
                                               f16* __restrict__ W2t) {
  const int LT[6] = {0, 1, 3, 4, 7, 10};
  __shared__ float t1[32][33], t2[32][33];
  int p = blockIdx.y;
  int bx = blockIdx.x & 15;
  int by = blockIdx.x >> 4;
  int tx = threadIdx.x & 31;
  int ty = threadIdx.x >> 5;  // 0..7
  size_t sbase = (size_t)LT[p] * HH;
  size_t dbase = (size_t)p * HH;
#pragma unroll
  for (int r = 0; r < 4; ++r) {
    int kk = bx * 32 + ty + r * 8;
    int nn = by * 32 + tx;
    t1[ty + r * 8][tx] = W1[sbase + (size_t)kk * 512 + nn];
    t2[ty + r * 8][tx] = W2[sbase + (size_t)kk * 512 + nn];
  }
  __syncthreads();
#pragma unroll
  for (int r = 0; r < 4; ++r) {
    int nn = by * 32 + ty + r * 8;
    int kk = bx * 32 + tx;
    W1t[dbase + (size_t)nn * 512 + kk] = (f16)t1[tx][ty + r * 8];
    W2t[dbase + (size_t)nn * 512 + kk] = (f16)t2[tx][ty + r * 8];
  }
}

// ---------------------------------------------------------------- CSR build
__global__ void k_hist(const int* __restrict__ edges, int* __restrict__ deg) {
  const int TMAP[4] = {0, 1, 3, 4};
  int c = blockIdx.y;
  int t = TMAP[c];
  int e = blockIdx.x * 256 + threadIdx.x;
  if (e < NEDGE) {
    int dst = edges[(size_t)t * 2 * NEDGE + NEDGE + e];
    atomicAdd(&deg[c * NNODES + dst], 1);
  }
}

__global__ void k_scan(const int* __restrict__ deg, int* __restrict__ offs,
                       int* __restrict__ cursor) {
  int c = blockIdx.x;
  const int* d = deg + (size_t)c * NNODES;
  int* o = offs + (size_t)c * NNODES;
  int* cu = cursor + (size_t)c * NNODES;
  __shared__ int sums[256];
  int tid = threadIdx.x;
  const int CH = 79;
  int start = tid * CH;
  int end = min(start + CH, NNODES);
  int s = 0;
  for (int i = start; i < end; ++i) s += d[i];
  sums[tid] = s;
  __syncthreads();
  for (int off = 1; off < 256; off <<= 1) {
    int v = (tid >= off) ? sums[tid - off] : 0;
    __syncthreads();
    sums[tid] += v;
    __syncthreads();
  }
  int run = sums[tid] - s;
  for (int i = start; i < end; ++i) {
    o[i] = run;
    cu[i] = run;
    run += d[i];
  }
}

__global__ void k_scatter(const int* __restrict__ edges, int* __restrict__ cursor,
                          int* __restrict__ csr) {
  const int TMAP[4] = {0, 1, 3, 4};
  int c = blockIdx.y;
  int t = TMAP[c];
  int e = blockIdx.x * 256 + threadIdx.x;
  if (e < NEDGE) {
    int src = edges[(size_t)t * 2 * NEDGE + e];
    int dst = edges[(size_t)t * 2 * NEDGE + NEDGE + e];
    int slot = atomicAdd(&cursor[c * NNODES + dst], 1);
    csr[(size_t)c * NEDGE + slot] = src;
  }
}

// ---------------------------------------------------------------- aggregation
struct AggSlot {
  const f16* dst;
  const f16* dst2;   // nullable: base = relu(dst+dst2)
  const f16* src1;
  const int* offs1;
  const int* rend1;
  const int* csr1;
  f16* out1;
  const f16* src2;   // nullable: second list sharing base
  const int* offs2;
  const int* rend2;
  const int* csr2;
  f16* out2;
};
struct AggBatch { AggSlot s[3]; };

__device__ __forceinline__ void agg_list(const f16* __restrict__ hs,
                                         const int* __restrict__ cs,
                                         int e, int e1, int lane,
                                         const float* __restrict__ base,
                                         f16* __restrict__ outp) {
  float acc[8];
#pragma unroll
  for (int q = 0; q < 8; ++q) acc[q] = base[q];
  for (; e + 3 < e1; e += 4) {
    int s0 = cs[e], s1 = cs[e + 1], s2 = cs[e + 2], s3 = cs[e + 3];
    f16x8 u0 = *(const f16x8*)(hs + (size_t)s0 * HDIM + lane * 8);
    f16x8 u1 = *(const f16x8*)(hs + (size_t)s1 * HDIM + lane * 8);
    f16x8 u2 = *(const f16x8*)(hs + (size_t)s2 * HDIM + lane * 8);
    f16x8 u3 = *(const f16x8*)(hs + (size_t)s3 * HDIM + lane * 8);
#pragma unroll
    for (int q = 0; q < 8; ++q)
      acc[q] += ((float)u0[q] + (float)u1[q]) + ((float)u2[q] + (float)u3[q]);
  }
  for (; e < e1; ++e) {
    int s0 = cs[e];
    f16x8 u0 = *(const f16x8*)(hs + (size_t)s0 * HDIM + lane * 8);
#pragma unroll
    for (int q = 0; q < 8; ++q) acc[q] += (float)u0[q];
  }
  f16x8 o;
#pragma unroll
  for (int q = 0; q < 8; ++q) o[q] = (f16)acc[q];
  *(f16x8*)outp = o;
}

__global__ __launch_bounds__(256) void k_agg(AggBatch ab) {
  const AggSlot sl = ab.s[blockIdx.y];
  int i = blockIdx.x * 4 + (threadIdx.x >> 6);
  int lane = threadIdx.x & 63;
  const size_t off = (size_t)i * HDIM + lane * 8;
  float base[8];
  f16x8 v = *(const f16x8*)(sl.dst + off);
  if (sl.dst2) {
    f16x8 v2 = *(const f16x8*)(sl.dst2 + off);
#pragma unroll
    for (int q = 0; q < 8; ++q) base[q] = fmaxf((float)v[q] + (float)v2[q], 0.f);
  } else {
#pragma unroll
    for (int q = 0; q < 8; ++q) base[q] = (float)v[q];
  }
  agg_list(sl.src1, sl.csr1, sl.offs1[i], sl.rend1[i], lane, base, sl.out1 + off);
  if (sl.src2)
    agg_list(sl.src2, sl.csr2, sl.offs2[i], sl.rend2[i], lane, base, sl.out2 + off);
}

// ---------------------------------------------------------------- GEMM (C = A @ Bt^T)
// Tile 256(M) x 256(N), BK=32, 512 threads = 8 waves, each 64x128 (4x8 frags).
// A [M,K] f16 row-major, Bt [512,K] f16 row-major.
// flags: 1=relu, 4=f16 out via LDS-bounce (else f32 direct).
// Grid: (2 n-blocks, ceil(M/256) m-blocks, z).
struct GemmBatch {
  const f16* A[6];
  const f16* B[6];
  const float* bias[6];
  void* D[6];
  int flags[6];
};

__global__ __launch_bounds__(512, 1) void k_gemm(GemmBatch gb, int M, int K) {
  __shared__ __align__(16) char smem[65536];  // A: 2x16KB @0; B: 2x16KB @32768
  const int z = blockIdx.z;
  const f16* __restrict__ A = gb.A[z];
  const f16* __restrict__ Bt = gb.B[z];
  const int flags = gb.flags[z];
  const int tid = threadIdx.x;
  const int lane = tid & 63;
  const int wave = tid >> 6;       // 0..7
  const int n0 = blockIdx.x * 256;
  const int m0 = blockIdx.y * 256;
  const int wm = wave & 3, wn = wave >> 2;  // wave covers rows wm*64.., cols wn*128..
  const int fr = lane & 15, fq = lane >> 4;

  // staging: each wave stages 32 rows of A and 32 rows of B per K-iter (2 calls each)
  const int lr = lane >> 2;
  const int lc = (lane & 3) * 8;
  const f16* gA0 = A + (size_t)min(m0 + wave * 32 + lr, M - 1) * K + lc;
  const f16* gA1 = A + (size_t)min(m0 + wave * 32 + 16 + lr, M - 1) * K + lc;
  const f16* gB0 = Bt + (size_t)(n0 + wave * 32 + lr) * K + lc;
  const f16* gB1 = Bt + (size_t)(n0 + wave * 32 + 16 + lr) * K + lc;

  f32x4 acc[4][8];
#pragma unroll
  for (int a = 0; a < 4; ++a)
#pragma unroll
    for (int b = 0; b < 8; ++b) acc[a][b] = (f32x4){0.f, 0.f, 0.f, 0.f};

  auto stage = [&](int b, int kk) {
    char* bufA = smem + b * 16384;
    char* bufB = smem + 32768 + b * 16384;
    async_lds16(gA0 + kk, bufA + wave * 2048);
    async_lds16(gA1 + kk, bufA + wave * 2048 + 1024);
    async_lds16(gB0 + kk, bufB + wave * 2048);
    async_lds16(gB1 + kk, bufB + wave * 2048 + 1024);
  };

  const int nb = K >> 5;
  stage(0, 0);
  for (int i = 0; i < nb; ++i) {
    const int cur = i & 1;
    if (i + 1 < nb) {
      stage(cur ^ 1, (i + 1) << 5);
      asm volatile("s_waitcnt vmcnt(4)" ::: "memory");
    } else {
      asm volatile("s_waitcnt vmcnt(0)" ::: "memory");
    }
    asm volatile("s_barrier" ::: "memory");
    const f16* lA = (const f16*)(smem + cur * 16384);
    const f16* lB = (const f16*)(smem + 32768 + cur * 16384);
    f16x8 af[4], bf[8];
#pragma unroll
    for (int t = 0; t < 4; ++t)
      af[t] = *(const f16x8*)&lA[(wm * 64 + t * 16 + fr) * 32 + fq * 8];
#pragma unroll
    for (int t = 0; t < 8; ++t)
      bf[t] = *(const f16x8*)&lB[(wn * 128 + t * 16 + fr) * 32 + fq * 8];
#pragma unroll
    for (int mt = 0; mt < 4; ++mt)
#pragma unroll
      for (int nt = 0; nt < 8; ++nt)
        acc[mt][nt] = __builtin_amdgcn_mfma_f32_16x16x32_f16(af[mt], bf[nt], acc[mt][nt], 0, 0, 0);
    asm volatile("s_barrier" ::: "memory");
  }

  const float* __restrict__ bias = gb.bias[z];

  if (flags & 4) {
    // f16 out via LDS bounce: 4 passes of 64 rows, padded stride 264 f16 (33KB)
    f16* tile = (f16*)smem;
#pragma unroll
    for (int pass = 0; pass < 4; ++pass) {
      if (wm == pass) {
#pragma unroll
        for (int nt = 0; nt < 8; ++nt) {
          const int cl = wn * 128 + nt * 16 + fr;
          const float bv = bias[n0 + cl];
#pragma unroll
          for (int mt = 0; mt < 4; ++mt) {
#pragma unroll
            for (int r = 0; r < 4; ++r) {
              float v = acc[mt][nt][r] + bv;
              if (flags & 1) v = fmaxf(v, 0.f);
              tile[(mt * 16 + fq * 4 + r) * 264 + cl] = (f16)v;
            }
          }
        }
      }
      __syncthreads();
#pragma unroll
      for (int q = 0; q < 4; ++q) {
        int idx = q * 512 + tid;
        int row = idx >> 5;
        int c8 = idx & 31;
        int grow = m0 + pass * 64 + row;
        f16x8 val = *(const f16x8*)&tile[row * 264 + c8 * 8];
        if (grow < M)
          *(f16x8*)((f16*)gb.D[z] + (size_t)grow * HDIM + n0 + c8 * 8) = val;
      }
      __syncthreads();
    }
  } else {
#pragma unroll
    for (int nt = 0; nt < 8; ++nt) {
      const int col = n0 + wn * 128 + nt * 16 + fr;
      const float bv = bias[col];
#pragma unroll
      for (int mt = 0; mt < 4; ++mt) {
        const int rowb = m0 + wm * 64 + mt * 16 + fq * 4;
#pragma unroll
        for (int r = 0; r < 4; ++r) {
          int row = rowb + r;
          if (row < M) {
            float v = acc[mt][nt][r] + bv;
            if (flags & 1) v = fmaxf(v, 0.f);
            ((float*)gb.D[z])[(size_t)row * HDIM + col] = v;
          }
        }
      }
    }
  }
}

// ---------------------------------------------------------------- head
__global__ __launch_bounds__(256) void k_head(const float* __restrict__ oa,
                                              const float* __restrict__ ob,
                                              const float* __restrict__ Wout,
                                              const float* __restrict__ bout,
                                              float* __restrict__ y) {
  int i = blockIdx.x * 4 + (threadIdx.x >> 6);
  int lane = threadIdx.x & 63;
  const float4* ra = (const float4*)(oa + (size_t)i * HDIM);
  const float4* rb = (const float4*)(ob + (size_t)i * HDIM);
  const float4* w = (const float4*)Wout;
  float s = 0.f;
#pragma unroll
  for (int h = 0; h < 2; ++h) {
    float4 a = ra[h * 64 + lane], b = rb[h * 64 + lane], ww = w[h * 64 + lane];
    s += fmaxf(a.x + b.x, 0.f) * ww.x + fmaxf(a.y + b.y, 0.f) * ww.y +
         fmaxf(a.z + b.z, 0.f) * ww.z + fmaxf(a.w + b.w, 0.f) * ww.w;
  }
#pragma unroll
  for (int m = 32; m; m >>= 1) s += __shfl_xor(s, m, 64);
  if (lane == 0) y[i] = s + bout[0];
}

// ---------------------------------------------------------------- launch
extern "C" void kernel_launch(void* const* d_in, const int* in_sizes, int n_in,
                              void* d_out, int out_size, void* d_ws, size_t ws_size,
                              hipStream_t stream) {
  const float* x_all = (const float*)d_in[0];
  const float* W_in = (const float*)d_in[1];
  const float* b_in = (const float*)d_in[2];
  const float* W1 = (const float*)d_in[3];
  const float* b1 = (const float*)d_in[4];
  const float* W2 = (const float*)d_in[5];
  const float* b2 = (const float*)d_in[6];
  const float* W_out = (const float*)d_in[7];
  const float* b_out = (const float*)d_in[8];
  const int* edges = (const int*)d_in[9];

  // ---- workspace carve (~207 MB)
  char* p = (char*)d_ws;
  auto take = [&](size_t bytes) {
    char* r = p;
    p += (bytes + 255) & ~(size_t)255;
    return r;
  };
  f16* xb = (f16*)take((size_t)5 * NNODES * FIN * 2);
  f16* Wint = (f16*)take((size_t)5 * HDIM * FIN * 2);
  f16* W1t = (f16*)take((size_t)6 * HH * 2);
  f16* W2t = (f16*)take((size_t)6 * HH * 2);
  int* deg = (int*)take((size_t)4 * NNODES * 4);
  int* offs = (int*)take((size_t)4 * NNODES * 4);
  int* cursor = (int*)take((size_t)4 * NNODES * 4);
  int* csr = (int*)take((size_t)4 * NEDGE * 4);
  f16* pool = (f16*)take((size_t)9 * SLICE * 2);
  auto P = [&](int s) { return pool + (size_t)s * SLICE; };

  // ---- prep + CSR
  k_prep<<<25953, 256, 0, stream>>>(x_all, xb, W_in, Wint, deg);
  k_cvt_w<<<dim3(256, 6), 256, 0, stream>>>(W1, W2, W1t, W2t);
  k_hist<<<dim3(625, 4), 256, 0, stream>>>(edges, deg);
  k_scan<<<4, 256, 0, stream>>>(deg, offs, cursor);
  k_scatter<<<dim3(625, 4), 256, 0, stream>>>(edges, cursor, csr);

  // ---- input projection: h0 types {0->P0,1->P1,2->P2,3->P3,4->P7}
  {
    const int hs[5] = {0, 1, 2, 3, 7};
    GemmBatch g{};
    for (int t = 0; t < 5; ++t) {
      g.A[t] = xb + (size_t)t * NNODES * FIN;
      g.B[t] = Wint + (size_t)t * HDIM * FIN;
      g.bias[t] = b_in + (size_t)t * HDIM;
      g.D[t] = P(hs[t]);
      g.flags[t] = 1 | 4;
    }
    k_gemm<<<dim3(2, 79, 5), 512, 0, stream>>>(g, NNODES, FIN);
  }

  // ---- layer 0 aggregations: slot0 pair(t1->P4, t4->P5, dst P0); slot1 t0->P6; slot2 t3->P8
  {
    AggBatch a{};
    a.s[0].dst = P(0);
    a.s[0].src1 = P(1); a.s[0].offs1 = offs + 1 * NNODES;
    a.s[0].rend1 = cursor + 1 * NNODES; a.s[0].csr1 = csr + (size_t)1 * NEDGE;
    a.s[0].out1 = P(4);
    a.s[0].src2 = P(3); a.s[0].offs2 = offs + 3 * NNODES;
    a.s[0].rend2 = cursor + 3 * NNODES; a.s[0].csr2 = csr + (size_t)3 * NEDGE;
    a.s[0].out2 = P(5);
    a.s[1].dst = P(1);
    a.s[1].src1 = P(7); a.s[1].offs1 = offs + 0 * NNODES;
    a.s[1].rend1 = cursor + 0 * NNODES; a.s[1].csr1 = csr + (size_t)0 * NEDGE;
    a.s[1].out1 = P(6);
    a.s[2].dst = P(3);
    a.s[2].src1 = P(2); a.s[2].offs1 = offs + 2 * NNODES;
    a.s[2].rend1 = cursor + 2 * NNODES; a.s[2].csr1 = csr + (size_t)2 * NEDGE;
    a.s[2].out1 = P(8);
    k_agg<<<dim3(5000, 3), 256, 0, stream>>>(a);
  }

  // ---- layer 0 MLP first GEMMs: A {P4,P5,P6,P8} -> z {P0,P1,P2,P3}
  {
    const int aj[4] = {4, 5, 6, 8};
    const int wj[4] = {1, 3, 0, 2};
    const int bj[4] = {1, 4, 0, 3};
    GemmBatch g{};
    for (int j = 0; j < 4; ++j) {
      g.A[j] = P(aj[j]);
      g.B[j] = W1t + (size_t)wj[j] * HH;
      g.bias[j] = b1 + (size_t)bj[j] * HDIM;
      g.D[j] = P(j);
      g.flags[j] = 1 | 4;
    }
    k_gemm<<<dim3(2, 79, 4), 512, 0, stream>>>(g, NNODES, HDIM);
  }

  // ---- layer 0 second GEMMs: ya->P4, yb->P5 (no relu); h1_t1->P6, h1_t3->P7 (relu)
  {
    const int wj[4] = {1, 3, 0, 2};
    const int bj[4] = {1, 4, 0, 3};
    const int dj[4] = {4, 5, 6, 7};
    const int fl[4] = {4, 4, 1 | 4, 1 | 4};
    GemmBatch g{};
    for (int j = 0; j < 4; ++j) {
      g.A[j] = P(j);
      g.B[j] = W2t + (size_t)wj[j] * HH;
      g.bias[j] = b2 + (size_t)bj[j] * HDIM;
      g.D[j] = P(dj[j]);
      g.flags[j] = fl[j];
    }
    k_gemm<<<dim3(2, 79, 4), 512, 0, stream>>>(g, NNODES, HDIM);
  }

  // ---- layer 1 aggregation: dst = relu(P4+P5); srcs P6,P7 -> P0,P1
  {
    AggBatch a{};
    a.s[0].dst = P(4); a.s[0].dst2 = P(5);
    a.s[0].src1 = P(6); a.s[0].offs1 = offs + 1 * NNODES;
    a.s[0].rend1 = cursor + 1 * NNODES; a.s[0].csr1 = csr + (size_t)1 * NEDGE;
    a.s[0].out1 = P(0);
    a.s[0].src2 = P(7); a.s[0].offs2 = offs + 3 * NNODES;
    a.s[0].rend2 = cursor + 3 * NNODES; a.s[0].csr2 = csr + (size_t)3 * NEDGE;
    a.s[0].out2 = P(1);
    k_agg<<<dim3(5000, 1), 256, 0, stream>>>(a);
  }

  // ---- layer 1 MLP first GEMMs: {P0,P1} -> {P2,P3}
  {
    const int wj[2] = {4, 5};
    const int bj[2] = {7, 10};
    GemmBatch g{};
    for (int j = 0; j < 2; ++j) {
      g.A[j] = P(j);
      g.B[j] = W1t + (size_t)wj[j] * HH;
      g.bias[j] = b1 + (size_t)bj[j] * HDIM;
      g.D[j] = P(2 + j);
      g.flags[j] = 1 | 4;
    }
    k_gemm<<<dim3(2, 79, 2), 512, 0, stream>>>(g, NNODES, HDIM);
  }

  // ---- layer 1 second GEMMs (z=2, f32 outputs): oa -> P4/P5, ob -> P6/P7
  float* oa = (float*)P(4);
  float* ob = (float*)P(6);
  {
    GemmBatch g{};
    g.A[0] = P(2); g.B[0] = W2t + (size_t)4 * HH;
    g.bias[0] = b2 + (size_t)7 * HDIM; g.D[0] = oa; g.flags[0] = 0;
    g.A[1] = P(3); g.B[1] = W2t + (size_t)5 * HH;
    g.bias[1] = b2 + (size_t)10 * HDIM; g.D[1] = ob; g.flags[1] = 0;
    k_gemm<<<dim3(2, 79, 2), 512, 0, stream>>>(g, NNODES, HDIM);
  }

  // ---- head
  k_head<<<5000, 256, 0, stream>>>(oa, ob, W_out, b_out, (float*)d_out);
}

// Round 6
// 611.496 us; speedup vs baseline: 1.1663x; 1.1663x over previous
//
#include <hip/hip_runtime.h>

#define NNODES 20000
#define FIN 64
#define HDIM 512
#define NEDGE 160000

typedef _Float16 f16;
typedef _Float16 f16x8 __attribute__((ext_vector_type(8)));
typedef float f32x4 __attribute__((ext_vector_type(4)));

#define SLICE ((size_t)NNODES * HDIM)
#define HH ((size_t)HDIM * HDIM)

// ---------------------------------------------------------------- helpers
__device__ __forceinline__ void async_lds16(const void* g, void* lds_base) {
  __builtin_amdgcn_global_load_lds(
      (const __attribute__((address_space(1))) void*)g,
      (__attribute__((address_space(3))) void*)lds_base, 16, 0, 0);
}

// ---------------------------------------------------------------- fused prep
// blocks [0,313): zero deg
// [313,25313): cvt x -> f16
// [25313,25953): W_in [5][64][512] -> [5][512][64] f16
// [25953,27489): W1/W2 tiled transpose -> f16, 6 used (l,t) slots
__global__ __launch_bounds__(256) void k_prep(
    const float* __restrict__ x, f16* __restrict__ xb,
    const float* __restrict__ Win, f16* __restrict__ Wint,
    const float* __restrict__ W1, const float* __restrict__ W2,
    f16* __restrict__ W1t, f16* __restrict__ W2t, int* __restrict__ deg) {
  __shared__ float t1[32][33], t2[32][33];
  int b = blockIdx.x;
  if (b < 313) {
    int i = b * 256 + threadIdx.x;
    if (i < 4 * NNODES) deg[i] = 0;
  } else if (b < 25313) {
    int i = (b - 313) * 256 + threadIdx.x;
    xb[i] = (f16)x[i];
  } else if (b < 25953) {
    int i = (b - 25313) * 256 + threadIdx.x;
    int t = i >> 15;
    int rem = i & 32767;
    int nn = rem >> 6;
    int kk = rem & 63;
    Wint[i] = (f16)Win[(size_t)t * 32768 + (size_t)kk * 512 + nn];
  } else {
    const int LT[6] = {0, 1, 3, 4, 7, 10};
    int b2 = b - 25953;
    int p = b2 >> 8;
    int tile = b2 & 255;
    int bx = tile & 15;
    int by = tile >> 4;
    int tx = threadIdx.x & 31;
    int ty = threadIdx.x >> 5;  // 0..7
    size_t sbase = (size_t)LT[p] * HH;
    size_t dbase = (size_t)p * HH;
#pragma unroll
    for (int r = 0; r < 4; ++r) {
      int kk = bx * 32 + ty + r * 8;
      int nn = by * 32 + tx;
      t1[ty + r * 8][tx] = W1[sbase + (size_t)kk * 512 + nn];
      t2[ty + r * 8][tx] = W2[sbase + (size_t)kk * 512 + nn];
    }
    __syncthreads();
#pragma unroll
    for (int r = 0; r < 4; ++r) {
      int nn = by * 32 + ty + r * 8;
      int kk = bx * 32 + tx;
      W1t[dbase + (size_t)nn * 512 + kk] = (f16)t1[tx][ty + r * 8];
      W2t[dbase + (size_t)nn * 512 + kk] = (f16)t2[tx][ty + r * 8];
    }
  }
}

// ---------------------------------------------------------------- CSR build
__global__ void k_hist(const int* __restrict__ edges, int* __restrict__ deg) {
  const int TMAP[4] = {0, 1, 3, 4};
  int c = blockIdx.y;
  int t = TMAP[c];
  int e = blockIdx.x * 256 + threadIdx.x;
  if (e < NEDGE) {
    int dst = edges[(size_t)t * 2 * NEDGE + NEDGE + e];
    atomicAdd(&deg[c * NNODES + dst], 1);
  }
}

__global__ void k_scan(const int* __restrict__ deg, int* __restrict__ offs,
                       int* __restrict__ cursor) {
  int c = blockIdx.x;
  const int* d = deg + (size_t)c * NNODES;
  int* o = offs + (size_t)c * NNODES;
  int* cu = cursor + (size_t)c * NNODES;
  __shared__ int sums[256];
  int tid = threadIdx.x;
  const int CH = 79;
  int start = tid * CH;
  int end = min(start + CH, NNODES);
  int s = 0;
  for (int i = start; i < end; ++i) s += d[i];
  sums[tid] = s;
  __syncthreads();
  for (int off = 1; off < 256; off <<= 1) {
    int v = (tid >= off) ? sums[tid - off] : 0;
    __syncthreads();
    sums[tid] += v;
    __syncthreads();
  }
  int run = sums[tid] - s;
  for (int i = start; i < end; ++i) {
    o[i] = run;
    cu[i] = run;
    run += d[i];
  }
}

__global__ void k_scatter(const int* __restrict__ edges, int* __restrict__ cursor,
                          int* __restrict__ csr) {
  const int TMAP[4] = {0, 1, 3, 4};
  int c = blockIdx.y;
  int t = TMAP[c];
  int e = blockIdx.x * 256 + threadIdx.x;
  if (e < NEDGE) {
    int src = edges[(size_t)t * 2 * NEDGE + e];
    int dst = edges[(size_t)t * 2 * NEDGE + NEDGE + e];
    int slot = atomicAdd(&cursor[c * NNODES + dst], 1);
    csr[(size_t)c * NEDGE + slot] = src;
  }
}

// ---------------------------------------------------------------- aggregation
struct AggSlot {
  const f16* dst;
  const f16* dst2;   // nullable: base = relu(dst+dst2)
  const f16* src1;
  const int* offs1;
  const int* rend1;
  const int* csr1;
  f16* out1;
  const f16* src2;   // nullable: second list sharing base
  const int* offs2;
  const int* rend2;
  const int* csr2;
  f16* out2;
};
struct AggBatch { AggSlot s[3]; };

__device__ __forceinline__ void agg_list(const f16* __restrict__ hs,
                                         const int* __restrict__ cs,
                                         int e, int e1, int lane,
                                         const float* __restrict__ base,
                                         f16* __restrict__ outp) {
  float acc[8];
#pragma unroll
  for (int q = 0; q < 8; ++q) acc[q] = base[q];
  for (; e + 3 < e1; e += 4) {
    int s0 = cs[e], s1 = cs[e + 1], s2 = cs[e + 2], s3 = cs[e + 3];
    f16x8 u0 = *(const f16x8*)(hs + (size_t)s0 * HDIM + lane * 8);
    f16x8 u1 = *(const f16x8*)(hs + (size_t)s1 * HDIM + lane * 8);
    f16x8 u2 = *(const f16x8*)(hs + (size_t)s2 * HDIM + lane * 8);
    f16x8 u3 = *(const f16x8*)(hs + (size_t)s3 * HDIM + lane * 8);
#pragma unroll
    for (int q = 0; q < 8; ++q)
      acc[q] += ((float)u0[q] + (float)u1[q]) + ((float)u2[q] + (float)u3[q]);
  }
  for (; e < e1; ++e) {
    int s0 = cs[e];
    f16x8 u0 = *(const f16x8*)(hs + (size_t)s0 * HDIM + lane * 8);
#pragma unroll
    for (int q = 0; q < 8; ++q) acc[q] += (float)u0[q];
  }
  f16x8 o;
#pragma unroll
  for (int q = 0; q < 8; ++q) o[q] = (f16)acc[q];
  *(f16x8*)outp = o;
}

__global__ __launch_bounds__(256) void k_agg(AggBatch ab) {
  const AggSlot sl = ab.s[blockIdx.y];
  int i = blockIdx.x * 4 + (threadIdx.x >> 6);
  int lane = threadIdx.x & 63;
  const size_t off = (size_t)i * HDIM + lane * 8;
  float base[8];
  f16x8 v = *(const f16x8*)(sl.dst + off);
  if (sl.dst2) {
    f16x8 v2 = *(const f16x8*)(sl.dst2 + off);
#pragma unroll
    for (int q = 0; q < 8; ++q) base[q] = fmaxf((float)v[q] + (float)v2[q], 0.f);
  } else {
#pragma unroll
    for (int q = 0; q < 8; ++q) base[q] = (float)v[q];
  }
  agg_list(sl.src1, sl.csr1, sl.offs1[i], sl.rend1[i], lane, base, sl.out1 + off);
  if (sl.src2)
    agg_list(sl.src2, sl.csr2, sl.offs2[i], sl.rend2[i], lane, base, sl.out2 + off);
}

// ---------------------------------------------------------------- GEMM (C = A @ Bt^T)
// Tile 128(M) x 256(N), BK=32, 256 threads = 4 waves, each 64x128 (4x8 frags).
// A [M,K] f16 row-major, Bt [512,K] f16 row-major.
// flags: 1=relu, 4=f16 out via LDS-bounce (else f32 direct).
// Grid: (2 n-blocks, ceil(M/128) m-blocks, z).  [round-4 measured-best config]
struct GemmBatch {
  const f16* A[6];
  const f16* B[6];
  const float* bias[6];
  void* D[6];
  int flags[6];
};

__global__ __launch_bounds__(256, 2) void k_gemm(GemmBatch gb, int M, int K) {
  __shared__ __align__(16) char smem[49152];  // A: 2x8KB @0; B: 2x16KB @16384
  const int z = blockIdx.z;
  const f16* __restrict__ A = gb.A[z];
  const f16* __restrict__ Bt = gb.B[z];
  const int flags = gb.flags[z];
  const int tid = threadIdx.x;
  const int lane = tid & 63;
  const int wave = tid >> 6;
  const int n0 = blockIdx.x * 256;
  const int m0 = blockIdx.y * 128;
  const int wm = wave & 1, wn = wave >> 1;
  const int fr = lane & 15, fq = lane >> 4;

  const int lr = lane >> 2;
  const int lc = (lane & 3) * 8;
  const f16* gA0 = A + (size_t)min(m0 + (wave * 2 + 0) * 16 + lr, M - 1) * K + lc;
  const f16* gA1 = A + (size_t)min(m0 + (wave * 2 + 1) * 16 + lr, M - 1) * K + lc;
  const f16* gB0 = Bt + (size_t)(n0 + (wave * 4 + 0) * 16 + lr) * K + lc;
  const f16* gB1 = Bt + (size_t)(n0 + (wave * 4 + 1) * 16 + lr) * K + lc;
  const f16* gB2 = Bt + (size_t)(n0 + (wave * 4 + 2) * 16 + lr) * K + lc;
  const f16* gB3 = Bt + (size_t)(n0 + (wave * 4 + 3) * 16 + lr) * K + lc;

  f32x4 acc[4][8];
#pragma unroll
  for (int a = 0; a < 4; ++a)
#pragma unroll
    for (int b = 0; b < 8; ++b) acc[a][b] = (f32x4){0.f, 0.f, 0.f, 0.f};

  auto stage = [&](int b, int kk) {
    char* bufA = smem + b * 8192;
    char* bufB = smem + 16384 + b * 16384;
    async_lds16(gA0 + kk, bufA + (wave * 2 + 0) * 1024);
    async_lds16(gA1 + kk, bufA + (wave * 2 + 1) * 1024);
    async_lds16(gB0 + kk, bufB + (wave * 4 + 0) * 1024);
    async_lds16(gB1 + kk, bufB + (wave * 4 + 1) * 1024);
    async_lds16(gB2 + kk, bufB + (wave * 4 + 2) * 1024);
    async_lds16(gB3 + kk, bufB + (wave * 4 + 3) * 1024);
  };

  const int nb = K >> 5;
  stage(0, 0);
  for (int i = 0; i < nb; ++i) {
    const int cur = i & 1;
    if (i + 1 < nb) {
      stage(cur ^ 1, (i + 1) << 5);
      asm volatile("s_waitcnt vmcnt(6)" ::: "memory");
    } else {
      asm volatile("s_waitcnt vmcnt(0)" ::: "memory");
    }
    asm volatile("s_barrier" ::: "memory");
    const f16* lA = (const f16*)(smem + cur * 8192);
    const f16* lB = (const f16*)(smem + 16384 + cur * 16384);
    f16x8 af[4], bf[8];
#pragma unroll
    for (int t = 0; t < 4; ++t)
      af[t] = *(const f16x8*)&lA[(wm * 64 + t * 16 + fr) * 32 + fq * 8];
#pragma unroll
    for (int t = 0; t < 8; ++t)
      bf[t] = *(const f16x8*)&lB[(wn * 128 + t * 16 + fr) * 32 + fq * 8];
#pragma unroll
    for (int mt = 0; mt < 4; ++mt)
#pragma unroll
      for (int nt = 0; nt < 8; ++nt)
        acc[mt][nt] = __builtin_amdgcn_mfma_f32_16x16x32_f16(af[mt], bf[nt], acc[mt][nt], 0, 0, 0);
    asm volatile("s_barrier" ::: "memory");
  }

  const float* __restrict__ bias = gb.bias[z];

  if (flags & 4) {
    f16* tile = (f16*)smem;
#pragma unroll
    for (int pass = 0; pass < 2; ++pass) {
      if (wm == pass) {
#pragma unroll
        for (int nt = 0; nt < 8; ++nt) {
          const int cl = wn * 128 + nt * 16 + fr;
          const float bv = bias[n0 + cl];
#pragma unroll
          for (int mt = 0; mt < 4; ++mt) {
#pragma unroll
            for (int r = 0; r < 4; ++r) {
              float v = acc[mt][nt][r] + bv;
              if (flags & 1) v = fmaxf(v, 0.f);
              tile[(mt * 16 + fq * 4 + r) * 264 + cl] = (f16)v;
            }
          }
        }
      }
      __syncthreads();
#pragma unroll
      for (int q = 0; q < 8; ++q) {
        int idx = q * 256 + tid;
        int row = idx >> 5;
        int c8 = idx & 31;
        int grow = m0 + pass * 64 + row;
        f16x8 val = *(const f16x8*)&tile[row * 264 + c8 * 8];
        if (grow < M)
          *(f16x8*)((f16*)gb.D[z] + (size_t)grow * HDIM + n0 + c8 * 8) = val;
      }
      __syncthreads();
    }
  } else {
#pragma unroll
    for (int nt = 0; nt < 8; ++nt) {
      const int col = n0 + wn * 128 + nt * 16 + fr;
      const float bv = bias[col];
#pragma unroll
      for (int mt = 0; mt < 4; ++mt) {
        const int rowb = m0 + wm * 64 + mt * 16 + fq * 4;
#pragma unroll
        for (int r = 0; r < 4; ++r) {
          int row = rowb + r;
          if (row < M) {
            float v = acc[mt][nt][r] + bv;
            if (flags & 1) v = fmaxf(v, 0.f);
            ((float*)gb.D[z])[(size_t)row * HDIM + col] = v;
          }
        }
      }
    }
  }
}

// ---------------------------------------------------------------- head
// y = relu(oa + ob) @ W_out + b_out   (oa, ob f16 [20000,512])
__global__ __launch_bounds__(256) void k_head(const f16* __restrict__ oa,
                                              const f16* __restrict__ ob,
                                              const float* __restrict__ Wout,
                                              const float* __restrict__ bout,
                                              float* __restrict__ y) {
  int i = blockIdx.x * 4 + (threadIdx.x >> 6);
  int lane = threadIdx.x & 63;
  f16x8 a = *(const f16x8*)(oa + (size_t)i * HDIM + lane * 8);
  f16x8 b = *(const f16x8*)(ob + (size_t)i * HDIM + lane * 8);
  const float4* w = (const float4*)(Wout + lane * 8);
  float4 w0 = w[0], w1 = w[1];
  float wv[8] = {w0.x, w0.y, w0.z, w0.w, w1.x, w1.y, w1.z, w1.w};
  float s = 0.f;
#pragma unroll
  for (int q = 0; q < 8; ++q)
    s += fmaxf((float)a[q] + (float)b[q], 0.f) * wv[q];
#pragma unroll
  for (int m = 32; m; m >>= 1) s += __shfl_xor(s, m, 64);
  if (lane == 0) y[i] = s + bout[0];
}

// ---------------------------------------------------------------- launch
extern "C" void kernel_launch(void* const* d_in, const int* in_sizes, int n_in,
                              void* d_out, int out_size, void* d_ws, size_t ws_size,
                              hipStream_t stream) {
  const float* x_all = (const float*)d_in[0];
  const float* W_in = (const float*)d_in[1];
  const float* b_in = (const float*)d_in[2];
  const float* W1 = (const float*)d_in[3];
  const float* b1 = (const float*)d_in[4];
  const float* W2 = (const float*)d_in[5];
  const float* b2 = (const float*)d_in[6];
  const float* W_out = (const float*)d_in[7];
  const float* b_out = (const float*)d_in[8];
  const int* edges = (const int*)d_in[9];

  // ---- workspace carve (~207 MB)
  char* p = (char*)d_ws;
  auto take = [&](size_t bytes) {
    char* r = p;
    p += (bytes + 255) & ~(size_t)255;
    return r;
  };
  f16* xb = (f16*)take((size_t)5 * NNODES * FIN * 2);
  f16* Wint = (f16*)take((size_t)5 * HDIM * FIN * 2);
  f16* W1t = (f16*)take((size_t)6 * HH * 2);
  f16* W2t = (f16*)take((size_t)6 * HH * 2);
  int* deg = (int*)take((size_t)4 * NNODES * 4);
  int* offs = (int*)take((size_t)4 * NNODES * 4);
  int* cursor = (int*)take((size_t)4 * NNODES * 4);
  int* csr = (int*)take((size_t)4 * NEDGE * 4);
  f16* pool = (f16*)take((size_t)9 * SLICE * 2);
  auto P = [&](int s) { return pool + (size_t)s * SLICE; };

  // ---- prep (fused) + CSR
  k_prep<<<27489, 256, 0, stream>>>(x_all, xb, W_in, Wint, W1, W2, W1t, W2t, deg);
  k_hist<<<dim3(625, 4), 256, 0, stream>>>(edges, deg);
  k_scan<<<4, 256, 0, stream>>>(deg, offs, cursor);
  k_scatter<<<dim3(625, 4), 256, 0, stream>>>(edges, cursor, csr);

  // ---- input projection: h0 types {0->P0,1->P1,2->P2,3->P3,4->P7}
  {
    const int hs[5] = {0, 1, 2, 3, 7};
    GemmBatch g{};
    for (int t = 0; t < 5; ++t) {
      g.A[t] = xb + (size_t)t * NNODES * FIN;
      g.B[t] = Wint + (size_t)t * HDIM * FIN;
      g.bias[t] = b_in + (size_t)t * HDIM;
      g.D[t] = P(hs[t]);
      g.flags[t] = 1 | 4;
    }
    k_gemm<<<dim3(2, 157, 5), 256, 0, stream>>>(g, NNODES, FIN);
  }

  // ---- layer 0 aggregations: slot0 pair(t1->P4, t4->P5, dst P0); slot1 t0->P6; slot2 t3->P8
  {
    AggBatch a{};
    a.s[0].dst = P(0);
    a.s[0].src1 = P(1); a.s[0].offs1 = offs + 1 * NNODES;
    a.s[0].rend1 = cursor + 1 * NNODES; a.s[0].csr1 = csr + (size_t)1 * NEDGE;
    a.s[0].out1 = P(4);
    a.s[0].src2 = P(3); a.s[0].offs2 = offs + 3 * NNODES;
    a.s[0].rend2 = cursor + 3 * NNODES; a.s[0].csr2 = csr + (size_t)3 * NEDGE;
    a.s[0].out2 = P(5);
    a.s[1].dst = P(1);
    a.s[1].src1 = P(7); a.s[1].offs1 = offs + 0 * NNODES;
    a.s[1].rend1 = cursor + 0 * NNODES; a.s[1].csr1 = csr + (size_t)0 * NEDGE;
    a.s[1].out1 = P(6);
    a.s[2].dst = P(3);
    a.s[2].src1 = P(2); a.s[2].offs1 = offs + 2 * NNODES;
    a.s[2].rend1 = cursor + 2 * NNODES; a.s[2].csr1 = csr + (size_t)2 * NEDGE;
    a.s[2].out1 = P(8);
    k_agg<<<dim3(5000, 3), 256, 0, stream>>>(a);
  }

  // ---- layer 0 MLP first GEMMs: A {P4,P5,P6,P8} -> z {P0,P1,P2,P3}
  {
    const int aj[4] = {4, 5, 6, 8};
    const int wj[4] = {1, 3, 0, 2};
    const int bj[4] = {1, 4, 0, 3};
    GemmBatch g{};
    for (int j = 0; j < 4; ++j) {
      g.A[j] = P(aj[j]);
      g.B[j] = W1t + (size_t)wj[j] * HH;
      g.bias[j] = b1 + (size_t)bj[j] * HDIM;
      g.D[j] = P(j);
      g.flags[j] = 1 | 4;
    }
    k_gemm<<<dim3(2, 157, 4), 256, 0, stream>>>(g, NNODES, HDIM);
  }

  // ---- layer 0 second GEMMs: ya->P4, yb->P5 (no relu); h1_t1->P6, h1_t3->P7 (relu)
  {
    const int wj[4] = {1, 3, 0, 2};
    const int bj[4] = {1, 4, 0, 3};
    const int dj[4] = {4, 5, 6, 7};
    const int fl[4] = {4, 4, 1 | 4, 1 | 4};
    GemmBatch g{};
    for (int j = 0; j < 4; ++j) {
      g.A[j] = P(j);
      g.B[j] = W2t + (size_t)wj[j] * HH;
      g.bias[j] = b2 + (size_t)bj[j] * HDIM;
      g.D[j] = P(dj[j]);
      g.flags[j] = fl[j];
    }
    k_gemm<<<dim3(2, 157, 4), 256, 0, stream>>>(g, NNODES, HDIM);
  }

  // ---- layer 1 aggregation: dst = relu(P4+P5); srcs P6,P7 -> P0,P1
  {
    AggBatch a{};
    a.s[0].dst = P(4); a.s[0].dst2 = P(5);
    a.s[0].src1 = P(6); a.s[0].offs1 = offs + 1 * NNODES;
    a.s[0].rend1 = cursor + 1 * NNODES; a.s[0].csr1 = csr + (size_t)1 * NEDGE;
    a.s[0].out1 = P(0);
    a.s[0].src2 = P(7); a.s[0].offs2 = offs + 3 * NNODES;
    a.s[0].rend2 = cursor + 3 * NNODES; a.s[0].csr2 = csr + (size_t)3 * NEDGE;
    a.s[0].out2 = P(1);
    k_agg<<<dim3(5000, 1), 256, 0, stream>>>(a);
  }

  // ---- layer 1 MLP first GEMMs: {P0,P1} -> {P2,P3}
  {
    const int wj[2] = {4, 5};
    const int bj[2] = {7, 10};
    GemmBatch g{};
    for (int j = 0; j < 2; ++j) {
      g.A[j] = P(j);
      g.B[j] = W1t + (size_t)wj[j] * HH;
      g.bias[j] = b1 + (size_t)bj[j] * HDIM;
      g.D[j] = P(2 + j);
      g.flags[j] = 1 | 4;
    }
    k_gemm<<<dim3(2, 157, 2), 256, 0, stream>>>(g, NNODES, HDIM);
  }

  // ---- layer 1 second GEMMs (z=2, f16 outputs): oa -> P4, ob -> P5
  f16* oa = P(4);
  f16* ob = P(5);
  {
    GemmBatch g{};
    g.A[0] = P(2); g.B[0] = W2t + (size_t)4 * HH;
    g.bias[0] = b2 + (size_t)7 * HDIM; g.D[0] = oa; g.flags[0] = 4;
    g.A[1] = P(3); g.B[1] = W2t + (size_t)5 * HH;
    g.bias[1] = b2 + (size_t)10 * HDIM; g.D[1] = ob; g.flags[1] = 4;
    k_gemm<<<dim3(2, 157, 2), 256, 0, stream>>>(g, NNODES, HDIM);
  }

  // ---- head
  k_head<<<5000, 256, 0, stream>>>(oa, ob, W_out, b_out, (float*)d_out);
}

// Round 7
// 610.086 us; speedup vs baseline: 1.1690x; 1.0023x over previous
//
#include <hip/hip_runtime.h>

#define NNODES 20000
#define FIN 64
#define HDIM 512
#define NEDGE 160000

typedef _Float16 f16;
typedef _Float16 f16x8 __attribute__((ext_vector_type(8)));
typedef _Float16 f16x4 __attribute__((ext_vector_type(4)));
typedef float f32x4 __attribute__((ext_vector_type(4)));

#define SLICE ((size_t)NNODES * HDIM)
#define HH ((size_t)HDIM * HDIM)

// ---------------------------------------------------------------- helpers
__device__ __forceinline__ void async_lds16(const void* g, void* lds_base) {
  __builtin_amdgcn_global_load_lds(
      (const __attribute__((address_space(1))) void*)g,
      (__attribute__((address_space(3))) void*)lds_base, 16, 0, 0);
}

// ---------------------------------------------------------------- fused prep
// blocks [0,313): zero deg
// [313,25313): cvt x -> f16
// [25313,25953): W_in [5][64][512] -> [5][512][64] f16
// [25953,27489): W1/W2 tiled transpose -> f16.
//   W1t slots p*HH ld512, p: 0=(0,0) 1=(0,1) 2=(0,3) 3=(0,4) 4=(1,1) 5=(1,4)
//   W2t: (0,0)->slot0 ld512; (0,3)->slot1 ld512; (0,1)->cat@slot2 ld1024 co0;
//        (0,4)->cat@slot2 ld1024 co512; (1,1)->slot4 ld512; (1,4)->slot5 ld512
__global__ __launch_bounds__(256) void k_prep(
    const float* __restrict__ x, f16* __restrict__ xb,
    const float* __restrict__ Win, f16* __restrict__ Wint,
    const float* __restrict__ W1, const float* __restrict__ W2,
    f16* __restrict__ W1t, f16* __restrict__ W2t, int* __restrict__ deg) {
  __shared__ float t1[32][33], t2[32][33];
  int b = blockIdx.x;
  if (b < 313) {
    int i = b * 256 + threadIdx.x;
    if (i < 4 * NNODES) deg[i] = 0;
  } else if (b < 25313) {
    int i = (b - 313) * 256 + threadIdx.x;
    xb[i] = (f16)x[i];
  } else if (b < 25953) {
    int i = (b - 25313) * 256 + threadIdx.x;
    int t = i >> 15;
    int rem = i & 32767;
    int nn = rem >> 6;
    int kk = rem & 63;
    Wint[i] = (f16)Win[(size_t)t * 32768 + (size_t)kk * 512 + nn];
  } else {
    const int LT[6] = {0, 1, 3, 4, 7, 10};
    const int W2BASE[6] = {0, 2, 1, 2, 4, 5};   // in HH units
    const int W2LD[6] = {512, 1024, 512, 1024, 512, 512};
    const int W2CO[6] = {0, 0, 0, 512, 0, 0};
    int b2 = b - 25953;
    int p = b2 >> 8;
    int tile = b2 & 255;
    int bx = tile & 15;
    int by = tile >> 4;
    int tx = threadIdx.x & 31;
    int ty = threadIdx.x >> 5;  // 0..7
    size_t sbase = (size_t)LT[p] * HH;
    size_t dbase1 = (size_t)p * HH;
    size_t dbase2 = (size_t)W2BASE[p] * HH;
    int ld2 = W2LD[p], co2 = W2CO[p];
#pragma unroll
    for (int r = 0; r < 4; ++r) {
      int kk = bx * 32 + ty + r * 8;
      int nn = by * 32 + tx;
      t1[ty + r * 8][tx] = W1[sbase + (size_t)kk * 512 + nn];
      t2[ty + r * 8][tx] = W2[sbase + (size_t)kk * 512 + nn];
    }
    __syncthreads();
#pragma unroll
    for (int r = 0; r < 4; ++r) {
      int nn = by * 32 + ty + r * 8;
      int kk = bx * 32 + tx;
      W1t[dbase1 + (size_t)nn * 512 + kk] = (f16)t1[tx][ty + r * 8];
      W2t[dbase2 + (size_t)nn * ld2 + co2 + kk] = (f16)t2[tx][ty + r * 8];
    }
  }
}

// ---------------------------------------------------------------- CSR build
__global__ void k_hist(const int* __restrict__ edges, int* __restrict__ deg) {
  const int TMAP[4] = {0, 1, 3, 4};
  int c = blockIdx.y;
  int t = TMAP[c];
  int e = blockIdx.x * 256 + threadIdx.x;
  if (e < NEDGE) {
    int dst = edges[(size_t)t * 2 * NEDGE + NEDGE + e];
    atomicAdd(&deg[c * NNODES + dst], 1);
  }
}

__global__ void k_scan(const int* __restrict__ deg, int* __restrict__ offs,
                       int* __restrict__ cursor) {
  int c = blockIdx.x;
  const int* d = deg + (size_t)c * NNODES;
  int* o = offs + (size_t)c * NNODES;
  int* cu = cursor + (size_t)c * NNODES;
  __shared__ int sums[256];
  int tid = threadIdx.x;
  const int CH = 79;
  int start = tid * CH;
  int end = min(start + CH, NNODES);
  int s = 0;
  for (int i = start; i < end; ++i) s += d[i];
  sums[tid] = s;
  __syncthreads();
  for (int off = 1; off < 256; off <<= 1) {
    int v = (tid >= off) ? sums[tid - off] : 0;
    __syncthreads();
    sums[tid] += v;
    __syncthreads();
  }
  int run = sums[tid] - s;
  for (int i = start; i < end; ++i) {
    o[i] = run;
    cu[i] = run;
    run += d[i];
  }
}

__global__ void k_scatter(const int* __restrict__ edges, int* __restrict__ cursor,
                          int* __restrict__ csr) {
  const int TMAP[4] = {0, 1, 3, 4};
  int c = blockIdx.y;
  int t = TMAP[c];
  int e = blockIdx.x * 256 + threadIdx.x;
  if (e < NEDGE) {
    int src = edges[(size_t)t * 2 * NEDGE + e];
    int dst = edges[(size_t)t * 2 * NEDGE + NEDGE + e];
    int slot = atomicAdd(&cursor[c * NNODES + dst], 1);
    csr[(size_t)c * NEDGE + slot] = src;
  }
}

// ---------------------------------------------------------------- aggregation
// Column-split: 2 waves per dst row, each covers a 256-col half (f16x4/lane).
struct AggSlot {
  const f16* dst;
  const f16* dst2;   // nullable: base = relu(dst+dst2)
  const f16* src1;
  const int* offs1;
  const int* rend1;
  const int* csr1;
  f16* out1;
  const f16* src2;   // nullable: second list sharing base
  const int* offs2;
  const int* rend2;
  const int* csr2;
  f16* out2;
};
struct AggBatch { AggSlot s[3]; };

__device__ __forceinline__ void agg_list(const f16* __restrict__ hs,
                                         const int* __restrict__ cs,
                                         int e, int e1, int col,
                                         const float* __restrict__ base,
                                         f16* __restrict__ outp) {
  float acc[4];
#pragma unroll
  for (int q = 0; q < 4; ++q) acc[q] = base[q];
  for (; e + 3 < e1; e += 4) {
    int s0 = cs[e], s1 = cs[e + 1], s2 = cs[e + 2], s3 = cs[e + 3];
    f16x4 u0 = *(const f16x4*)(hs + (size_t)s0 * HDIM + col);
    f16x4 u1 = *(const f16x4*)(hs + (size_t)s1 * HDIM + col);
    f16x4 u2 = *(const f16x4*)(hs + (size_t)s2 * HDIM + col);
    f16x4 u3 = *(const f16x4*)(hs + (size_t)s3 * HDIM + col);
#pragma unroll
    for (int q = 0; q < 4; ++q)
      acc[q] += ((float)u0[q] + (float)u1[q]) + ((float)u2[q] + (float)u3[q]);
  }
  for (; e < e1; ++e) {
    int s0 = cs[e];
    f16x4 u0 = *(const f16x4*)(hs + (size_t)s0 * HDIM + col);
#pragma unroll
    for (int q = 0; q < 4; ++q) acc[q] += (float)u0[q];
  }
  f16x4 o;
#pragma unroll
  for (int q = 0; q < 4; ++q) o[q] = (f16)acc[q];
  *(f16x4*)outp = o;
}

__global__ __launch_bounds__(256) void k_agg(AggBatch ab) {
  const AggSlot sl = ab.s[blockIdx.y];
  int w = threadIdx.x >> 6;
  int i = blockIdx.x * 2 + (w >> 1);          // dst row
  int lane = threadIdx.x & 63;
  int col = (w & 1) * 256 + lane * 4;         // column within row
  const size_t off = (size_t)i * HDIM + col;
  float base[4];
  f16x4 v = *(const f16x4*)(sl.dst + off);
  if (sl.dst2) {
    f16x4 v2 = *(const f16x4*)(sl.dst2 + off);
#pragma unroll
    for (int q = 0; q < 4; ++q) base[q] = fmaxf((float)v[q] + (float)v2[q], 0.f);
  } else {
#pragma unroll
    for (int q = 0; q < 4; ++q) base[q] = (float)v[q];
  }
  agg_list(sl.src1, sl.csr1, sl.offs1[i], sl.rend1[i], col, base, sl.out1 + off);
  if (sl.src2)
    agg_list(sl.src2, sl.csr2, sl.offs2[i], sl.rend2[i], col, base, sl.out2 + off);
}

// ---------------------------------------------------------------- GEMM (C = A @ Bt^T)
// Tile 128(M) x 256(N), BK=32, 256 threads = 4 waves, each 64x128 (4x8 frags).
// A [M,K] f16 row-major (stride lda), Bt [512,K] f16 row-major (stride K).
// Per-z: K, lda, ldd, optional second bias. flags: 1=relu, 4=f16 out via LDS bounce.
struct GemmBatch {
  const f16* A[6];
  const f16* B[6];
  const float* bias[6];
  const float* bias2[6];
  void* D[6];
  int flags[6];
  int Kz[6];
  int lda[6];
  int ldd[6];
};

__global__ __launch_bounds__(256, 2) void k_gemm(GemmBatch gb, int M) {
  __shared__ __align__(16) char smem[49152];  // A: 2x8KB @0; B: 2x16KB @16384
  const int z = blockIdx.z;
  const f16* __restrict__ A = gb.A[z];
  const f16* __restrict__ Bt = gb.B[z];
  const int flags = gb.flags[z];
  const int K = gb.Kz[z];
  const int lda = gb.lda[z];
  const int ldd = gb.ldd[z];
  const int tid = threadIdx.x;
  const int lane = tid & 63;
  const int wave = tid >> 6;
  const int n0 = blockIdx.x * 256;
  const int m0 = blockIdx.y * 128;
  const int wm = wave & 1, wn = wave >> 1;
  const int fr = lane & 15, fq = lane >> 4;

  const int lr = lane >> 2;
  const int lc = (lane & 3) * 8;
  const f16* gA0 = A + (size_t)min(m0 + (wave * 2 + 0) * 16 + lr, M - 1) * lda + lc;
  const f16* gA1 = A + (size_t)min(m0 + (wave * 2 + 1) * 16 + lr, M - 1) * lda + lc;
  const f16* gB0 = Bt + (size_t)(n0 + (wave * 4 + 0) * 16 + lr) * K + lc;
  const f16* gB1 = Bt + (size_t)(n0 + (wave * 4 + 1) * 16 + lr) * K + lc;
  const f16* gB2 = Bt + (size_t)(n0 + (wave * 4 + 2) * 16 + lr) * K + lc;
  const f16* gB3 = Bt + (size_t)(n0 + (wave * 4 + 3) * 16 + lr) * K + lc;

  f32x4 acc[4][8];
#pragma unroll
  for (int a = 0; a < 4; ++a)
#pragma unroll
    for (int b = 0; b < 8; ++b) acc[a][b] = (f32x4){0.f, 0.f, 0.f, 0.f};

  auto stage = [&](int b, int kk) {
    char* bufA = smem + b * 8192;
    char* bufB = smem + 16384 + b * 16384;
    async_lds16(gA0 + kk, bufA + (wave * 2 + 0) * 1024);
    async_lds16(gA1 + kk, bufA + (wave * 2 + 1) * 1024);
    async_lds16(gB0 + kk, bufB + (wave * 4 + 0) * 1024);
    async_lds16(gB1 + kk, bufB + (wave * 4 + 1) * 1024);
    async_lds16(gB2 + kk, bufB + (wave * 4 + 2) * 1024);
    async_lds16(gB3 + kk, bufB + (wave * 4 + 3) * 1024);
  };

  const int nb = K >> 5;
  stage(0, 0);
  for (int i = 0; i < nb; ++i) {
    const int cur = i & 1;
    if (i + 1 < nb) {
      stage(cur ^ 1, (i + 1) << 5);
      asm volatile("s_waitcnt vmcnt(6)" ::: "memory");
    } else {
      asm volatile("s_waitcnt vmcnt(0)" ::: "memory");
    }
    asm volatile("s_barrier" ::: "memory");
    const f16* lA = (const f16*)(smem + cur * 8192);
    const f16* lB = (const f16*)(smem + 16384 + cur * 16384);
    f16x8 af[4], bf[8];
#pragma unroll
    for (int t = 0; t < 4; ++t)
      af[t] = *(const f16x8*)&lA[(wm * 64 + t * 16 + fr) * 32 + fq * 8];
#pragma unroll
    for (int t = 0; t < 8; ++t)
      bf[t] = *(const f16x8*)&lB[(wn * 128 + t * 16 + fr) * 32 + fq * 8];
#pragma unroll
    for (int mt = 0; mt < 4; ++mt)
#pragma unroll
      for (int nt = 0; nt < 8; ++nt)
        acc[mt][nt] = __builtin_amdgcn_mfma_f32_16x16x32_f16(af[mt], bf[nt], acc[mt][nt], 0, 0, 0);
    asm volatile("s_barrier" ::: "memory");
  }

  const float* __restrict__ bias = gb.bias[z];
  const float* __restrict__ bias2 = gb.bias2[z];

  if (flags & 4) {
    f16* tile = (f16*)smem;
#pragma unroll
    for (int pass = 0; pass < 2; ++pass) {
      if (wm == pass) {
#pragma unroll
        for (int nt = 0; nt < 8; ++nt) {
          const int cl = wn * 128 + nt * 16 + fr;
          float bv = bias[n0 + cl];
          if (bias2) bv += bias2[n0 + cl];
#pragma unroll
          for (int mt = 0; mt < 4; ++mt) {
#pragma unroll
            for (int r = 0; r < 4; ++r) {
              float v = acc[mt][nt][r] + bv;
              if (flags & 1) v = fmaxf(v, 0.f);
              tile[(mt * 16 + fq * 4 + r) * 264 + cl] = (f16)v;
            }
          }
        }
      }
      __syncthreads();
#pragma unroll
      for (int q = 0; q < 8; ++q) {
        int idx = q * 256 + tid;
        int row = idx >> 5;
        int c8 = idx & 31;
        int grow = m0 + pass * 64 + row;
        f16x8 val = *(const f16x8*)&tile[row * 264 + c8 * 8];
        if (grow < M)
          *(f16x8*)((f16*)gb.D[z] + (size_t)grow * ldd + n0 + c8 * 8) = val;
      }
      __syncthreads();
    }
  } else {
#pragma unroll
    for (int nt = 0; nt < 8; ++nt) {
      const int col = n0 + wn * 128 + nt * 16 + fr;
      float bv = bias[col];
      if (bias2) bv += bias2[col];
#pragma unroll
      for (int mt = 0; mt < 4; ++mt) {
        const int rowb = m0 + wm * 64 + mt * 16 + fq * 4;
#pragma unroll
        for (int r = 0; r < 4; ++r) {
          int row = rowb + r;
          if (row < M) {
            float v = acc[mt][nt][r] + bv;
            if (flags & 1) v = fmaxf(v, 0.f);
            ((float*)gb.D[z])[(size_t)row * ldd + col] = v;
          }
        }
      }
    }
  }
}

// ---------------------------------------------------------------- head
// y = relu(oa + ob) @ W_out + b_out   (oa, ob f16 [20000,512])
__global__ __launch_bounds__(256) void k_head(const f16* __restrict__ oa,
                                              const f16* __restrict__ ob,
                                              const float* __restrict__ Wout,
                                              const float* __restrict__ bout,
                                              float* __restrict__ y) {
  int i = blockIdx.x * 4 + (threadIdx.x >> 6);
  int lane = threadIdx.x & 63;
  f16x8 a = *(const f16x8*)(oa + (size_t)i * HDIM + lane * 8);
  f16x8 b = *(const f16x8*)(ob + (size_t)i * HDIM + lane * 8);
  const float4* w = (const float4*)(Wout + lane * 8);
  float4 w0 = w[0], w1 = w[1];
  float wv[8] = {w0.x, w0.y, w0.z, w0.w, w1.x, w1.y, w1.z, w1.w};
  float s = 0.f;
#pragma unroll
  for (int q = 0; q < 8; ++q)
    s += fmaxf((float)a[q] + (float)b[q], 0.f) * wv[q];
#pragma unroll
  for (int m = 32; m; m >>= 1) s += __shfl_xor(s, m, 64);
  if (lane == 0) y[i] = s + bout[0];
}

// ---------------------------------------------------------------- launch
extern "C" void kernel_launch(void* const* d_in, const int* in_sizes, int n_in,
                              void* d_out, int out_size, void* d_ws, size_t ws_size,
                              hipStream_t stream) {
  const float* x_all = (const float*)d_in[0];
  const float* W_in = (const float*)d_in[1];
  const float* b_in = (const float*)d_in[2];
  const float* W1 = (const float*)d_in[3];
  const float* b1 = (const float*)d_in[4];
  const float* W2 = (const float*)d_in[5];
  const float* b2 = (const float*)d_in[6];
  const float* W_out = (const float*)d_in[7];
  const float* b_out = (const float*)d_in[8];
  const int* edges = (const int*)d_in[9];

  // ---- workspace carve (~207 MB)
  char* p = (char*)d_ws;
  auto take = [&](size_t bytes) {
    char* r = p;
    p += (bytes + 255) & ~(size_t)255;
    return r;
  };
  f16* xb = (f16*)take((size_t)5 * NNODES * FIN * 2);
  f16* Wint = (f16*)take((size_t)5 * HDIM * FIN * 2);
  f16* W1t = (f16*)take((size_t)6 * HH * 2);
  f16* W2t = (f16*)take((size_t)6 * HH * 2);
  int* deg = (int*)take((size_t)4 * NNODES * 4);
  int* offs = (int*)take((size_t)4 * NNODES * 4);
  int* cursor = (int*)take((size_t)4 * NNODES * 4);
  int* csr = (int*)take((size_t)4 * NEDGE * 4);
  f16* pool = (f16*)take((size_t)9 * SLICE * 2);
  auto P = [&](int s) { return pool + (size_t)s * SLICE; };
  f16* Z0 = P(0);  // [20000][1024] spanning P0,P1 (col-concat of z_t1|z_t4)

  // ---- prep (fused) + CSR
  k_prep<<<27489, 256, 0, stream>>>(x_all, xb, W_in, Wint, W1, W2, W1t, W2t, deg);
  k_hist<<<dim3(625, 4), 256, 0, stream>>>(edges, deg);
  k_scan<<<4, 256, 0, stream>>>(deg, offs, cursor);
  k_scatter<<<dim3(625, 4), 256, 0, stream>>>(edges, cursor, csr);

  // ---- input projection: h0 types {0->P0,1->P1,2->P2,3->P3,4->P7}
  {
    const int hs[5] = {0, 1, 2, 3, 7};
    GemmBatch g{};
    for (int t = 0; t < 5; ++t) {
      g.A[t] = xb + (size_t)t * NNODES * FIN;
      g.B[t] = Wint + (size_t)t * HDIM * FIN;
      g.bias[t] = b_in + (size_t)t * HDIM;
      g.D[t] = P(hs[t]);
      g.flags[t] = 1 | 4;
      g.Kz[t] = FIN; g.lda[t] = FIN; g.ldd[t] = HDIM;
    }
    k_gemm<<<dim3(2, 157, 5), 256, 0, stream>>>(g, NNODES);
  }

  // ---- layer 0 aggregations: slot0 pair(t1->P4, t4->P5, dst P0); slot1 t0->P6; slot2 t3->P8
  {
    AggBatch a{};
    a.s[0].dst = P(0);
    a.s[0].src1 = P(1); a.s[0].offs1 = offs + 1 * NNODES;
    a.s[0].rend1 = cursor + 1 * NNODES; a.s[0].csr1 = csr + (size_t)1 * NEDGE;
    a.s[0].out1 = P(4);
    a.s[0].src2 = P(3); a.s[0].offs2 = offs + 3 * NNODES;
    a.s[0].rend2 = cursor + 3 * NNODES; a.s[0].csr2 = csr + (size_t)3 * NEDGE;
    a.s[0].out2 = P(5);
    a.s[1].dst = P(1);
    a.s[1].src1 = P(7); a.s[1].offs1 = offs + 0 * NNODES;
    a.s[1].rend1 = cursor + 0 * NNODES; a.s[1].csr1 = csr + (size_t)0 * NEDGE;
    a.s[1].out1 = P(6);
    a.s[2].dst = P(3);
    a.s[2].src1 = P(2); a.s[2].offs1 = offs + 2 * NNODES;
    a.s[2].rend1 = cursor + 2 * NNODES; a.s[2].csr1 = csr + (size_t)2 * NEDGE;
    a.s[2].out1 = P(8);
    k_agg<<<dim3(10000, 3), 256, 0, stream>>>(a);
  }

  // ---- layer 0 MLP first GEMMs (z=4): t1->Z0 col0, t4->Z0 col512, t0->P2, t3->P3
  {
    GemmBatch g{};
    // j0: t1
    g.A[0] = P(4); g.B[0] = W1t + 1 * HH; g.bias[0] = b1 + 1 * HDIM;
    g.D[0] = Z0; g.flags[0] = 1 | 4; g.Kz[0] = 512; g.lda[0] = 512; g.ldd[0] = 1024;
    // j1: t4
    g.A[1] = P(5); g.B[1] = W1t + 3 * HH; g.bias[1] = b1 + 4 * HDIM;
    g.D[1] = Z0 + 512; g.flags[1] = 1 | 4; g.Kz[1] = 512; g.lda[1] = 512; g.ldd[1] = 1024;
    // j2: t0
    g.A[2] = P(6); g.B[2] = W1t + 0 * HH; g.bias[2] = b1 + 0 * HDIM;
    g.D[2] = P(2); g.flags[2] = 1 | 4; g.Kz[2] = 512; g.lda[2] = 512; g.ldd[2] = 512;
    // j3: t3
    g.A[3] = P(8); g.B[3] = W1t + 2 * HH; g.bias[3] = b1 + 3 * HDIM;
    g.D[3] = P(3); g.flags[3] = 1 | 4; g.Kz[3] = 512; g.lda[3] = 512; g.ldd[3] = 512;
    k_gemm<<<dim3(2, 157, 4), 256, 0, stream>>>(g, NNODES);
  }

  // ---- layer 0 second GEMMs (z=3):
  // z0: h1_t0 = relu(Z0 @ [W2(0,1);W2(0,4)] + b2a + b2b) -> P4  (K=1024 concat)
  // z1: h1_t1 = relu(P2 @ W2(0,0) + b2) -> P5
  // z2: h1_t3 = relu(P3 @ W2(0,3) + b2) -> P6
  {
    GemmBatch g{};
    g.A[0] = Z0; g.B[0] = W2t + 2 * HH; g.bias[0] = b2 + 1 * HDIM;
    g.bias2[0] = b2 + 4 * HDIM; g.D[0] = P(4);
    g.flags[0] = 1 | 4; g.Kz[0] = 1024; g.lda[0] = 1024; g.ldd[0] = 512;
    g.A[1] = P(2); g.B[1] = W2t + 0 * HH; g.bias[1] = b2 + 0 * HDIM;
    g.D[1] = P(5); g.flags[1] = 1 | 4; g.Kz[1] = 512; g.lda[1] = 512; g.ldd[1] = 512;
    g.A[2] = P(3); g.B[2] = W2t + 1 * HH; g.bias[2] = b2 + 3 * HDIM;
    g.D[2] = P(6); g.flags[2] = 1 | 4; g.Kz[2] = 512; g.lda[2] = 512; g.ldd[2] = 512;
    k_gemm<<<dim3(2, 157, 3), 256, 0, stream>>>(g, NNODES);
  }

  // ---- layer 1 aggregation: base = P4 (h1_t0, already relu'd sum); srcs P5,P6 -> P0,P1
  {
    AggBatch a{};
    a.s[0].dst = P(4);
    a.s[0].src1 = P(5); a.s[0].offs1 = offs + 1 * NNODES;
    a.s[0].rend1 = cursor + 1 * NNODES; a.s[0].csr1 = csr + (size_t)1 * NEDGE;
    a.s[0].out1 = P(0);
    a.s[0].src2 = P(6); a.s[0].offs2 = offs + 3 * NNODES;
    a.s[0].rend2 = cursor + 3 * NNODES; a.s[0].csr2 = csr + (size_t)3 * NEDGE;
    a.s[0].out2 = P(1);
    k_agg<<<dim3(10000, 1), 256, 0, stream>>>(a);
  }

  // ---- layer 1 MLP first GEMMs (z=2): P0->P2, P1->P3
  {
    GemmBatch g{};
    g.A[0] = P(0); g.B[0] = W1t + 4 * HH; g.bias[0] = b1 + 7 * HDIM;
    g.D[0] = P(2); g.flags[0] = 1 | 4; g.Kz[0] = 512; g.lda[0] = 512; g.ldd[0] = 512;
    g.A[1] = P(1); g.B[1] = W1t + 5 * HH; g.bias[1] = b1 + 10 * HDIM;
    g.D[1] = P(3); g.flags[1] = 1 | 4; g.Kz[1] = 512; g.lda[1] = 512; g.ldd[1] = 512;
    k_gemm<<<dim3(2, 157, 2), 256, 0, stream>>>(g, NNODES);
  }

  // ---- layer 1 second GEMMs (z=2, f16 outputs, no relu): oa->P7, ob->P8
  f16* oa = P(7);
  f16* ob = P(8);
  {
    GemmBatch g{};
    g.A[0] = P(2); g.B[0] = W2t + 4 * HH; g.bias[0] = b2 + 7 * HDIM;
    g.D[0] = oa; g.flags[0] = 4; g.Kz[0] = 512; g.lda[0] = 512; g.ldd[0] = 512;
    g.A[1] = P(3); g.B[1] = W2t + 5 * HH; g.bias[1] = b2 + 10 * HDIM;
    g.D[1] = ob; g.flags[1] = 4; g.Kz[1] = 512; g.lda[1] = 512; g.ldd[1] = 512;
    k_gemm<<<dim3(2, 157, 2), 256, 0, stream>>>(g, NNODES);
  }

  // ---- head
  k_head<<<5000, 256, 0, stream>>>(oa, ob, W_out, b_out, (float*)d_out);
}